// Round 15
// baseline (142.935 us; speedup 1.0000x reference)
//
#include <hip/hip_runtime.h>

#define NROWS 131072
#define D 64
#define K 1024
#define NBLK 256

typedef __attribute__((ext_vector_type(8))) short short8;
typedef __attribute__((ext_vector_type(4))) float f32x4;
typedef unsigned int u32;

// ws layout (bytes):
//   [0, 1048576)        bhist int[256][1024]  per-block histograms (fully
//                                             overwritten every iteration)
//   [1048576, 1049600)  wavesum float[256]    per-block loss partials
// (prep_kernel is GONE — R21 fuses codebook prep into score; ehT/e2g/hist
//  no longer exist in ws.)

__device__ __forceinline__ unsigned short f2bf_rne(float f) {
    u32 u = __float_as_uint(f);
    u += 0x7fff + ((u >> 16) & 1);   // round-to-nearest-even
    return (unsigned short)(u >> 16);
}

__device__ __forceinline__ float b2f(short s) {
    return __uint_as_float(((u32)(unsigned short)s) << 16);
}

// R21 = R7 score path (3x reproduced: 122.1-124.1us total, 49.3-50us score)
// with the prep launch FUSED IN — the one never-isolated lever (launch
// boundary). No cross-block sync anywhere (the crashed fused-finalize is
// retired; this is a different, dependency-free fusion):
//  - A-fragments: each wave converts its 64 codes straight from E with the
//    SAME f2bf_rne -> bit-identical bf16 fragment values.
//  - e2 = -0.5||e||^2: per-lane 16-d partial (fused into the fragment loads)
//    + shfl_xor butterfly. Reassociated vs prep's order (~1ulp); the packed
//    score|code argmax quantizes scores to 22 bits (~1e-3 quanta) so a 1e-7
//    perturbation flips an argmax with P~1e-7/row -> expected flips ~0.01.
//  - epilogue: e-rows regenerated from E fp32 via the same RNE -> q bits
//    identical to the ehT gather.
//  - hist: per-block LDS histogram dumped to bhist[block][code] (coalesced,
//    fully overwritten -> robust to ws re-poisoning); finalize column-sums.
// Launches 3 -> 2. Score inner loop untouched.
__global__ __launch_bounds__(1024) void score_kernel(const float* __restrict__ X,
                                                     const float* __restrict__ E,
                                                     int* __restrict__ bhist,
                                                     float* __restrict__ wavesum,
                                                     float* __restrict__ q) {
    __shared__ unsigned short xbuf[2][8192];   // 2 x 16 KB: 128 rows x 64 d, frag order
    __shared__ float mrg[2][128 * 17];         // per-row packed best per wave (stride 17)
    __shared__ int idxl[2][128];               // winning code per row, double-buffered
    __shared__ int lhist[1024];                // block-local histogram
    __shared__ float redL[16];

    const int tid = threadIdx.x;
    const int wave = tid >> 6;
    const int lane = tid & 63;
    const int quad = lane >> 4;
    const int lc = lane & 15;
    const size_t row0 = (size_t)blockIdx.x * 512;

    lhist[tid] = 0;

    // ---- stage mapping: thread n -> LDS 16B unit n = (t=n>>7, o=(n>>4)&7,
    // ls=n&15) holding bf16 X[t*16+ls][o*8..+8]; global read fully coalesced.
    const int st = tid >> 7, so = (tid >> 4) & 7, sl = tid & 15;
    const int rowl = st * 16 + sl;             // this thread's staged row (0..127)
    const float* sbase = X + (row0 + (size_t)rowl) * D + so * 8;

    // ---- prologue: stage chunk 0 ----
    {
        float4 La = *(const float4*)(sbase);
        float4 Lb = *(const float4*)(sbase + 4);
        union { u32 u[4]; short8 v; } pk;
        pk.u[0] = __builtin_amdgcn_perm(__float_as_uint(La.y), __float_as_uint(La.x), 0x07060302);
        pk.u[1] = __builtin_amdgcn_perm(__float_as_uint(La.w), __float_as_uint(La.z), 0x07060302);
        pk.u[2] = __builtin_amdgcn_perm(__float_as_uint(Lb.y), __float_as_uint(Lb.x), 0x07060302);
        pk.u[3] = __builtin_amdgcn_perm(__float_as_uint(Lb.w), __float_as_uint(Lb.z), 0x07060302);
        *(short8*)((char*)&xbuf[0][0] + tid * 16) = pk.v;
    }

    // ---- fused prep: build fragments + e2 from E (fp32 [D][K], L2/L3-hot).
    // Lane loads E[d][code], d = ks*32+quad*8+j, code = cbase+ct*16+lc —
    // same values prep converted; f2bf_rne reproduces the exact bf16 bits.
    const int cbase = wave * 64;
    short8 ae[4][2];      // [code-tile][kslice]: code=tile*16+lc, d=ks*32+quad*8..+8
    f32x4 e2f[4];         // -0.5||e||^2 for codes tile*16+quad*4..+4 (MFMA C operand)
    {
        float tot[4];
#pragma unroll
        for (int ct = 0; ct < 4; ++ct) {
            const int code = cbase + ct * 16 + lc;
            float p = 0.f;
#pragma unroll
            for (int ks = 0; ks < 2; ++ks) {
                union { u32 u[4]; short8 v; } pk;
#pragma unroll
                for (int jj = 0; jj < 4; ++jj) {
                    float va = E[(size_t)(ks * 32 + quad * 8 + 2 * jj) * K + code];
                    float vb = E[(size_t)(ks * 32 + quad * 8 + 2 * jj + 1) * K + code];
                    p = fmaf(va, va, p);
                    p = fmaf(vb, vb, p);
                    pk.u[jj] = ((u32)f2bf_rne(vb) << 16) | (u32)f2bf_rne(va);
                }
                ae[ct][ks] = pk.v;
            }
            // lane holds 16 d's of this code; butterfly over quads -> all 64 d
            p += __shfl_xor(p, 16, 64);
            p += __shfl_xor(p, 32, 64);
            tot[ct] = p;    // e2-sum for code cbase+ct*16+lc (uniform over quads)
        }
#pragma unroll
        for (int ct = 0; ct < 4; ++ct)
#pragma unroll
            for (int r = 0; r < 4; ++r)
                e2f[ct][r] = -0.5f * __shfl(tot[ct], quad * 4 + r, 64);
    }
    const u32 cb0 = (u32)(cbase + quad * 4);

    __syncthreads();   // B1: chunk 0 staged + lhist zeroed

    float ls = 0.f;
    for (int c = 0; c < 4; ++c) {
        const int cur = c & 1;
        // issue-early global loads for chunk c+1 (land during compute)
        float4 La, Lb;
        if (c < 3) {
            La = *(const float4*)(sbase + (c + 1) * 8192);
            Lb = *(const float4*)(sbase + (c + 1) * 8192 + 4);
        }

        // ---- compute chunk c: pure ds_read + MFMA + max3 into bt8 ----
        float bt8[8];
        const char* bb = (const char*)&xbuf[cur][0];
#pragma unroll 2
        for (int t = 0; t < 8; ++t) {
            const char* bp = bb + t * 2048 + quad * 256 + lc * 16;
            short8 b0 = *(const short8*)(bp);           // ks0
            short8 b1 = *(const short8*)(bp + 1024);    // ks1
            float bt = -3.4e38f;
#pragma unroll
            for (int ct = 0; ct < 4; ++ct) {
                f32x4 acc = __builtin_amdgcn_mfma_f32_16x16x32_bf16(ae[ct][0], b0, e2f[ct], 0, 0, 0);
                acc = __builtin_amdgcn_mfma_f32_16x16x32_bf16(ae[ct][1], b1, acc, 0, 0, 0);
                // acc[r] = score(code = cb0 + ct*16 + r, xrow = t*16+lc)
                float p0 = __uint_as_float((__float_as_uint(acc[0]) & 0xFFFFFC00u) | (cb0 + ct * 16 + 0));
                float p1 = __uint_as_float((__float_as_uint(acc[1]) & 0xFFFFFC00u) | (cb0 + ct * 16 + 1));
                float p2 = __uint_as_float((__float_as_uint(acc[2]) & 0xFFFFFC00u) | (cb0 + ct * 16 + 2));
                float p3 = __uint_as_float((__float_as_uint(acc[3]) & 0xFFFFFC00u) | (cb0 + ct * 16 + 3));
                bt = fmaxf(bt, fmaxf(p0, p1));   // v_max3
                bt = fmaxf(bt, fmaxf(p2, p3));   // v_max3
            }
            bt8[t] = bt;
        }
        // ---- batched cross-lane reduce: 8 independent shfl chains ----
#pragma unroll
        for (int t = 0; t < 8; ++t) {
            float bt = bt8[t];
            bt = fmaxf(bt, __shfl_xor(bt, 16, 64));
            bt = fmaxf(bt, __shfl_xor(bt, 32, 64));
            if (lane < 16) mrg[cur][(t * 16 + lane) * 17 + wave] = bt;
        }
        __syncthreads();   // B2: mrg[cur] visible

        // ---- merge (128 thr, LDS hist) ∥ stage-write c+1 (all) ----
        if (tid < 128) {
            float m = mrg[cur][tid * 17];
#pragma unroll
            for (int w = 1; w < 16; ++w) m = fmaxf(m, mrg[cur][tid * 17 + w]);
            int kk = (int)(__float_as_uint(m) & 1023u);
            idxl[cur][tid] = kk;
            atomicAdd(&lhist[kk], 1);          // block-local, no global atomic
        }
        if (c < 3) {
            union { u32 u[4]; short8 v; } pk;
            pk.u[0] = __builtin_amdgcn_perm(__float_as_uint(La.y), __float_as_uint(La.x), 0x07060302);
            pk.u[1] = __builtin_amdgcn_perm(__float_as_uint(La.w), __float_as_uint(La.z), 0x07060302);
            pk.u[2] = __builtin_amdgcn_perm(__float_as_uint(Lb.y), __float_as_uint(Lb.x), 0x07060302);
            pk.u[3] = __builtin_amdgcn_perm(__float_as_uint(Lb.w), __float_as_uint(Lb.z), 0x07060302);
            *(short8*)((char*)&xbuf[cur ^ 1][0] + tid * 16) = pk.v;
        }
        __syncthreads();   // B3: idxl[cur] + staged chunk visible

        // ---- fused epilogue chunk c: q = bf16(E-row) regenerated via RNE;
        // x from the staged LDS slice; no X re-read, no ehT.
        {
            int kk = idxl[cur][rowl];                 // broadcast among 8 so-threads
            short8 xv = *(const short8*)(&xbuf[cur][tid * 8]);
            float4 qa, qb;
            float e0, dd;
#pragma unroll
            for (int i = 0; i < 4; ++i) {
                e0 = b2f((short)f2bf_rne(E[(size_t)(so * 8 + i) * K + kk]));
                dd = e0 - b2f(xv[i]);
                ls = fmaf(dd, dd, ls);
                ((float*)&qa)[i] = e0;
            }
#pragma unroll
            for (int i = 0; i < 4; ++i) {
                e0 = b2f((short)f2bf_rne(E[(size_t)(so * 8 + 4 + i) * K + kk]));
                dd = e0 - b2f(xv[4 + i]);
                ls = fmaf(dd, dd, ls);
                ((float*)&qb)[i] = e0;
            }
            float* qp = q + (row0 + (size_t)(c * 128 + rowl)) * D + so * 8;
            *(float4*)(qp) = qa;
            *(float4*)(qp + 4) = qb;
        }
    }

    // ---- dump block histogram (coalesced, fully overwrites its slice) ----
    bhist[blockIdx.x * 1024 + tid] = lhist[tid];

    // ---- block loss reduction ----
    for (int off = 32; off > 0; off >>= 1) ls += __shfl_down(ls, off, 64);
    if (lane == 0) redL[wave] = ls;
    __syncthreads();
    if (tid == 0) {
        float L = 0.f;
#pragma unroll
        for (int i = 0; i < 16; ++i) L += redL[i];
        wavesum[blockIdx.x] = L;
    }
}

__global__ __launch_bounds__(1024) void finalize_kernel(const int* __restrict__ bhist,
                                                        const float* __restrict__ wavesum,
                                                        float* __restrict__ out) {
    __shared__ float redH[16], redL[16];
    int tid = threadIdx.x;
    // column-sum the 256 per-block histograms (coalesced across tid per b)
    int h = 0;
#pragma unroll 4
    for (int b = 0; b < NBLK; ++b) h += bhist[b * 1024 + tid];
    float p = (float)h * (1.0f / (float)NROWS);
    float term = p * logf(p + 1e-10f);
    float ls = (tid < NBLK) ? wavesum[tid] : 0.f;
    for (int off = 32; off > 0; off >>= 1) {
        term += __shfl_down(term, off, 64);
        ls += __shfl_down(ls, off, 64);
    }
    int lane = tid & 63, wid = tid >> 6;
    if (lane == 0) { redH[wid] = term; redL[wid] = ls; }
    __syncthreads();
    if (tid == 0) {
        float H = 0.f, L = 0.f;
#pragma unroll
        for (int i = 0; i < 16; ++i) { H += redH[i]; L += redL[i]; }
        out[(size_t)NROWS * D + 0] = 2.0f * (L / (float)(NROWS * D));
        out[(size_t)NROWS * D + 1] = expf(-H);
    }
}

extern "C" void kernel_launch(void* const* d_in, const int* in_sizes, int n_in,
                              void* d_out, int out_size, void* d_ws, size_t ws_size,
                              hipStream_t stream) {
    const float* X = (const float*)d_in[0];   // [64,2048,64] fp32
    const float* E = (const float*)d_in[1];   // [64,1024]   fp32
    float* out = (float*)d_out;

    char* w = (char*)d_ws;
    int* bhist    = (int*)(w + 0);            // 1 MB
    float* wavesum = (float*)(w + 1048576);   // 1 KB

    score_kernel<<<NBLK, 1024, 0, stream>>>(X, E, bhist, wavesum, out);
    finalize_kernel<<<1, 1024, 0, stream>>>(bhist, wavesum, out);
}

// Round 16
// 123.892 us; speedup vs baseline: 1.1537x; 1.1537x over previous
//
#include <hip/hip_runtime.h>

#define NROWS 131072
#define D 64
#define K 1024

typedef __attribute__((ext_vector_type(8))) short short8;
typedef __attribute__((ext_vector_type(4))) float f32x4;
typedef unsigned int u32;

// ws layout (bytes):
//   [0, 131072)        ehT  ushort[1024][64]  bf16 codebook, [code][d]
//   [131072, 135168)   e2g  float[1024]       = -0.5*||e_k||^2
//   [135168, 139264)   hist int[1024]
//   [139264, 143360)   wavesum float[256]  (one per score block)

__device__ __forceinline__ unsigned short f2bf_rne(float f) {
    u32 u = __float_as_uint(f);
    u += 0x7fff + ((u >> 16) & 1);   // round-to-nearest-even
    return (unsigned short)(u >> 16);
}

__device__ __forceinline__ float b2f(short s) {
    return __uint_as_float(((u32)(unsigned short)s) << 16);
}

// 16 blocks x 256 threads: block handles 64 codes, thread = (code, d-quarter).
__global__ __launch_bounds__(256) void prep_kernel(const float* __restrict__ E,
                                                   unsigned short* __restrict__ ehT,
                                                   float* __restrict__ e2g,
                                                   int* __restrict__ hist) {
    __shared__ float ps[4][64];
    const int lane = threadIdx.x & 63;          // code offset within block
    const int w = threadIdx.x >> 6;             // d-quarter 0..3
    const int k = blockIdx.x * 64 + lane;
    float s = 0.f;
#pragma unroll
    for (int half = 0; half < 2; ++half) {
        short8 h8;
#pragma unroll
        for (int j = 0; j < 8; ++j) {
            float v = E[(w * 16 + half * 8 + j) * K + k];   // coalesced across lanes
            s = fmaf(v, v, s);
            h8[j] = (short)f2bf_rne(v);
        }
        *(short8*)(ehT + (size_t)k * D + w * 16 + half * 8) = h8;
    }
    ps[w][lane] = s;
    __syncthreads();
    if (w == 0) e2g[k] = -0.5f * (ps[0][lane] + ps[1][lane] + ps[2][lane] + ps[3][lane]);
    if (threadIdx.x < 64) hist[blockIdx.x * 64 + threadIdx.x] = 0;
}

// FINAL = R7 (best verified: 122.05-124.1us total, score 49.3-50us,
// reproduced 3x; absmax bit-exact 0.4326172).
// SESSION SUMMARY (16 rounds, 134 -> 122us):
//  KEPT: codebook-in-registers MFMA (A=codes, e2 as C operand), packed
//    score|code fmax argmax, fused per-chunk epilogue (q = bf16 codebook row,
//    no X re-read), batched shfl reduce, issue-early staging, 3-launch chain.
//  MEASURED DEAD: occupancy/TLP levers (pinned ~35% across 4/8/16-wave,
//    52-112 regs); barrier restructuring (5-9 barriers, superchunks);
//    nt-stores; prep-fusion (epilogue E-regather 32x worse than ehT, -20us);
//    finalize-fusion (container-fatal, retired); launch_bounds min-wave caps
//    (scratch spill poison); ct-outer order (8x LDS traffic).
//  PLATEAU: score ~49us with MFMA 13% / VALU 31% / HBM 14% — latency-bound
//    phase structure, not a pipe roofline; residual ~72us is harness-fixed.
__global__ __launch_bounds__(1024) void score_kernel(const float* __restrict__ X,
                                                     const unsigned short* __restrict__ ehT,
                                                     const float* __restrict__ e2g,
                                                     int* __restrict__ hist,
                                                     float* __restrict__ wavesum,
                                                     float* __restrict__ q) {
    __shared__ unsigned short xbuf[2][8192];   // 2 x 16 KB: 128 rows x 64 d, frag order
    __shared__ float mrg[2][128 * 17];         // per-row packed best per wave (stride 17)
    __shared__ int idxl[2][128];               // winning code per row, double-buffered
    __shared__ float redL[16];

    const int tid = threadIdx.x;
    const int wave = tid >> 6;
    const int lane = tid & 63;
    const int quad = lane >> 4;
    const int lc = lane & 15;
    const size_t row0 = (size_t)blockIdx.x * 512;

    // ---- stage mapping: thread n -> LDS 16B unit n = (t=n>>7, o=(n>>4)&7,
    // ls=n&15) holding bf16 X[t*16+ls][o*8..+8]; global read fully coalesced.
    const int st = tid >> 7, so = (tid >> 4) & 7, sl = tid & 15;
    const int rowl = st * 16 + sl;             // this thread's staged row (0..127)
    const float* sbase = X + (row0 + (size_t)rowl) * D + so * 8;

    // ---- prologue: stage chunk 0 ----
    {
        float4 La = *(const float4*)(sbase);
        float4 Lb = *(const float4*)(sbase + 4);
        union { u32 u[4]; short8 v; } pk;
        pk.u[0] = __builtin_amdgcn_perm(__float_as_uint(La.y), __float_as_uint(La.x), 0x07060302);
        pk.u[1] = __builtin_amdgcn_perm(__float_as_uint(La.w), __float_as_uint(La.z), 0x07060302);
        pk.u[2] = __builtin_amdgcn_perm(__float_as_uint(Lb.y), __float_as_uint(Lb.x), 0x07060302);
        pk.u[3] = __builtin_amdgcn_perm(__float_as_uint(Lb.w), __float_as_uint(Lb.z), 0x07060302);
        *(short8*)((char*)&xbuf[0][0] + tid * 16) = pk.v;
    }

    // ---- persistent codebook fragments: wave owns codes [wave*64, wave*64+64) ----
    const int cbase = wave * 64;
    short8 ae[4][2];      // [code-tile][kslice]: code=tile*16+lc, d=ks*32+quad*8..+8
    f32x4 e2f[4];         // -0.5||e||^2 for codes tile*16+quad*4..+4 (MFMA C operand)
#pragma unroll
    for (int ct = 0; ct < 4; ++ct) {
        const unsigned short* ap = ehT + ((size_t)(cbase + ct * 16 + lc) << 6) + quad * 8;
        ae[ct][0] = *(const short8*)(ap);
        ae[ct][1] = *(const short8*)(ap + 32);
        e2f[ct] = *(const f32x4*)(e2g + cbase + ct * 16 + quad * 4);
    }
    const u32 cb0 = (u32)(cbase + quad * 4);

    __syncthreads();   // B1: chunk 0 staged

    float ls = 0.f;
    for (int c = 0; c < 4; ++c) {
        const int cur = c & 1;
        // issue-early global loads for chunk c+1 (land during compute; the
        // vmcnt wait sits at the stage-write after B2, long past latency)
        float4 La, Lb;
        if (c < 3) {
            La = *(const float4*)(sbase + (c + 1) * 8192);
            Lb = *(const float4*)(sbase + (c + 1) * 8192 + 4);
        }

        // ---- compute chunk c: pure ds_read + MFMA + max3 into bt8 ----
        float bt8[8];
        const char* bb = (const char*)&xbuf[cur][0];
#pragma unroll 2
        for (int t = 0; t < 8; ++t) {
            const char* bp = bb + t * 2048 + quad * 256 + lc * 16;
            short8 b0 = *(const short8*)(bp);           // ks0
            short8 b1 = *(const short8*)(bp + 1024);    // ks1
            float bt = -3.4e38f;
#pragma unroll
            for (int ct = 0; ct < 4; ++ct) {
                f32x4 acc = __builtin_amdgcn_mfma_f32_16x16x32_bf16(ae[ct][0], b0, e2f[ct], 0, 0, 0);
                acc = __builtin_amdgcn_mfma_f32_16x16x32_bf16(ae[ct][1], b1, acc, 0, 0, 0);
                // acc[r] = score(code = cb0 + ct*16 + r, xrow = t*16+lc)
                float p0 = __uint_as_float((__float_as_uint(acc[0]) & 0xFFFFFC00u) | (cb0 + ct * 16 + 0));
                float p1 = __uint_as_float((__float_as_uint(acc[1]) & 0xFFFFFC00u) | (cb0 + ct * 16 + 1));
                float p2 = __uint_as_float((__float_as_uint(acc[2]) & 0xFFFFFC00u) | (cb0 + ct * 16 + 2));
                float p3 = __uint_as_float((__float_as_uint(acc[3]) & 0xFFFFFC00u) | (cb0 + ct * 16 + 3));
                bt = fmaxf(bt, fmaxf(p0, p1));   // v_max3
                bt = fmaxf(bt, fmaxf(p2, p3));   // v_max3
            }
            bt8[t] = bt;
        }
        // ---- batched cross-lane reduce: 8 independent shfl chains ----
#pragma unroll
        for (int t = 0; t < 8; ++t) {
            float bt = bt8[t];
            bt = fmaxf(bt, __shfl_xor(bt, 16, 64));
            bt = fmaxf(bt, __shfl_xor(bt, 32, 64));
            if (lane < 16) mrg[cur][(t * 16 + lane) * 17 + wave] = bt;
        }
        __syncthreads();   // B2: mrg[cur] visible

        // ---- merge (128 thr) ∥ stage-write c+1 (all) ----
        if (tid < 128) {
            float m = mrg[cur][tid * 17];
#pragma unroll
            for (int w = 1; w < 16; ++w) m = fmaxf(m, mrg[cur][tid * 17 + w]);
            int kk = (int)(__float_as_uint(m) & 1023u);
            idxl[cur][tid] = kk;
            atomicAdd(&hist[kk], 1);
        }
        if (c < 3) {
            union { u32 u[4]; short8 v; } pk;
            pk.u[0] = __builtin_amdgcn_perm(__float_as_uint(La.y), __float_as_uint(La.x), 0x07060302);
            pk.u[1] = __builtin_amdgcn_perm(__float_as_uint(La.w), __float_as_uint(La.z), 0x07060302);
            pk.u[2] = __builtin_amdgcn_perm(__float_as_uint(Lb.y), __float_as_uint(Lb.x), 0x07060302);
            pk.u[3] = __builtin_amdgcn_perm(__float_as_uint(Lb.w), __float_as_uint(Lb.z), 0x07060302);
            *(short8*)((char*)&xbuf[cur ^ 1][0] + tid * 16) = pk.v;
        }
        __syncthreads();   // B3: idxl[cur] + staged chunk visible

        // ---- fused epilogue chunk c: own staged slice; q = e_bf16; no X read.
        // Interleaves with the next chunk's compute (independent pipes).
        {
            int kk = idxl[cur][rowl];                 // broadcast among 8 so-threads
            short8 ev = *(const short8*)(ehT + ((size_t)kk << 6) + so * 8);
            short8 xv = *(const short8*)(&xbuf[cur][tid * 8]);
            float4 qa, qb;
            float e0, dd;
            e0 = b2f(ev[0]); dd = e0 - b2f(xv[0]); ls = fmaf(dd, dd, ls); qa.x = e0;
            e0 = b2f(ev[1]); dd = e0 - b2f(xv[1]); ls = fmaf(dd, dd, ls); qa.y = e0;
            e0 = b2f(ev[2]); dd = e0 - b2f(xv[2]); ls = fmaf(dd, dd, ls); qa.z = e0;
            e0 = b2f(ev[3]); dd = e0 - b2f(xv[3]); ls = fmaf(dd, dd, ls); qa.w = e0;
            e0 = b2f(ev[4]); dd = e0 - b2f(xv[4]); ls = fmaf(dd, dd, ls); qb.x = e0;
            e0 = b2f(ev[5]); dd = e0 - b2f(xv[5]); ls = fmaf(dd, dd, ls); qb.y = e0;
            e0 = b2f(ev[6]); dd = e0 - b2f(xv[6]); ls = fmaf(dd, dd, ls); qb.z = e0;
            e0 = b2f(ev[7]); dd = e0 - b2f(xv[7]); ls = fmaf(dd, dd, ls); qb.w = e0;
            float* qp = q + (row0 + (size_t)(c * 128 + rowl)) * D + so * 8;
            *(float4*)(qp) = qa;
            *(float4*)(qp + 4) = qb;
        }
    }

    // ---- block loss reduction ----
    for (int off = 32; off > 0; off >>= 1) ls += __shfl_down(ls, off, 64);
    if (lane == 0) redL[wave] = ls;
    __syncthreads();
    if (tid == 0) {
        float L = 0.f;
#pragma unroll
        for (int i = 0; i < 16; ++i) L += redL[i];
        wavesum[blockIdx.x] = L;
    }
}

__global__ __launch_bounds__(1024) void finalize_kernel(const int* __restrict__ hist,
                                                        const float* __restrict__ wavesum,
                                                        float* __restrict__ out) {
    __shared__ float redH[16], redL[16];
    int tid = threadIdx.x;
    float p = (float)hist[tid] * (1.0f / (float)NROWS);
    float term = p * logf(p + 1e-10f);
    float ls = (tid < 256) ? wavesum[tid] : 0.f;
    for (int off = 32; off > 0; off >>= 1) {
        term += __shfl_down(term, off, 64);
        ls += __shfl_down(ls, off, 64);
    }
    int lane = tid & 63, wid = tid >> 6;
    if (lane == 0) { redH[wid] = term; redL[wid] = ls; }
    __syncthreads();
    if (tid == 0) {
        float H = 0.f, L = 0.f;
#pragma unroll
        for (int i = 0; i < 16; ++i) { H += redH[i]; L += redL[i]; }
        out[(size_t)NROWS * D + 0] = 2.0f * (L / (float)(NROWS * D));
        out[(size_t)NROWS * D + 1] = expf(-H);
    }
}

extern "C" void kernel_launch(void* const* d_in, const int* in_sizes, int n_in,
                              void* d_out, int out_size, void* d_ws, size_t ws_size,
                              hipStream_t stream) {
    const float* X = (const float*)d_in[0];   // [64,2048,64] fp32
    const float* E = (const float*)d_in[1];   // [64,1024]   fp32
    float* out = (float*)d_out;

    char* w = (char*)d_ws;
    unsigned short* ehT = (unsigned short*)(w + 0);
    float* e2g          = (float*)(w + 131072);
    int* hist           = (int*)(w + 135168);
    float* wavesum      = (float*)(w + 139264);

    prep_kernel<<<16, 256, 0, stream>>>(E, ehT, e2g, hist);
    score_kernel<<<NROWS / 512, 1024, 0, stream>>>(X, ehT, e2g, hist, wavesum, out);
    finalize_kernel<<<1, 1024, 0, stream>>>(hist, wavesum, out);
}